// Round 15
// baseline (93.982 us; speedup 1.0000x reference)
//
#include <hip/hip_runtime.h>

typedef unsigned short u16;
typedef unsigned int u32;
typedef __attribute__((ext_vector_type(8))) short bf16x8;
typedef __attribute__((ext_vector_type(4))) float f32x4;
typedef __attribute__((ext_vector_type(4))) unsigned short u16x4;

#define DEVI __device__ __forceinline__

constexpr float L2GAMMA = -0.15200309344504997f; // log2(0.9)
constexpr float INV_SQRT_H = 0.0625f;            // 1/sqrt(256)

DEVI u16 f2bf(float x) {
  union { float f; unsigned u; } v; v.f = x;
  unsigned r = v.u + 0x7FFFu + ((v.u >> 16) & 1u);
  return (u16)(r >> 16);
}

// ===========================================================================
// Fragment-tiled operand layout (the whole point of this round):
//   frag f = m16*32 + k32  (m16: 16-row block, k32: 32-col K block)
//   stored as 512 u16; slot = lane l: holds  X[m16*16 + (l&15)][k32*32 +
//   (l>>4)*8 .. +7]  == exactly one wave's mfma_16x16x32 A/B fragment.
//   GEMM frag load = ONE contiguous 1KB per-wave global_load_dwordx4.
//   No LDS anywhere in the GEMM -> no barriers, no swizzles, no races.
// ===========================================================================

// ---- kernel 0a: x fp32 -> At (fragment-tiled bf16) -----------------------
// grid 8192 = 1024 m16-blocks x 8 k32-quads, 256 thr.
// Wave q handles frag (m16, quad*4+q): reads 16 rows x 128 B, writes 1KB
// fully coalesced.
__global__ void cvt_x_kernel(const float* __restrict__ x, u16* __restrict__ At) {
  const int blk = blockIdx.x;                 // 0..8191
  const int m16 = blk >> 3, quad = blk & 7;
  const int tid = threadIdx.x;
  const int lrow = tid & 15, lkg = (tid >> 4) & 3, q = tid >> 6;
  const int k32 = quad * 4 + q;
  const float* src = x + (size_t)(m16 * 16 + lrow) * 1024 + k32 * 32 + lkg * 8;
  float4 v0 = *(const float4*)src;
  float4 v1 = *(const float4*)(src + 4);
  u16* dst = At + (size_t)(m16 * 32 + k32) * 512 + (size_t)(tid & 63) * 8;
  u16x4 o0, o1;
  o0.x = f2bf(v0.x); o0.y = f2bf(v0.y); o0.z = f2bf(v0.z); o0.w = f2bf(v0.w);
  o1.x = f2bf(v1.x); o1.y = f2bf(v1.y); o1.z = f2bf(v1.z); o1.w = f2bf(v1.w);
  *(u16x4*)dst = o0;
  *(u16x4*)(dst + 4) = o1;
}

// ---- kernel 0b: W_Q|W_K|W_V -> Wt (fragment-tiled bf16, 768 rows) --------
// grid 384 = 48 n16-blocks x 8 quads, 256 thr.
__global__ void cvt_w_kernel(const float* __restrict__ wq, const float* __restrict__ wk,
                             const float* __restrict__ wv, u16* __restrict__ Wt) {
  const int blk = blockIdx.x;                 // 0..383
  const int n16 = blk >> 3, quad = blk & 7;
  const int tid = threadIdx.x;
  const int lrow = tid & 15, lkg = (tid >> 4) & 3, q = tid >> 6;
  const int k32 = quad * 4 + q;
  const int row = n16 * 16 + lrow;            // 0..767
  const int wsel = row >> 8, r = row & 255;
  const float* w = (wsel == 0) ? wq : ((wsel == 1) ? wk : wv);
  const float* src = w + (size_t)r * 1024 + k32 * 32 + lkg * 8;
  float4 v0 = *(const float4*)src;
  float4 v1 = *(const float4*)(src + 4);
  u16* dst = Wt + (size_t)(n16 * 32 + k32) * 512 + (size_t)(tid & 63) * 8;
  u16x4 o0, o1;
  o0.x = f2bf(v0.x); o0.y = f2bf(v0.y); o0.z = f2bf(v0.z); o0.w = f2bf(v0.w);
  o1.x = f2bf(v1.x); o1.y = f2bf(v1.y); o1.z = f2bf(v1.z); o1.w = f2bf(v1.w);
  *(u16x4*)dst = o0;
  *(u16x4*)(dst + 4) = o1;
}

// ---- kernel 1: QKV GEMM, NO-LDS direct frag-load -------------------------
// C[16384x768] = A * W^T from fragment-tiled At/Wt.
// BM=256 BN=192, 8 waves 2Mx4N (wave out 128x48), grid 256 = 1 WG/CU,
// XCD-chunked (4 co-XCD WGs share each A panel via L2; W L2-resident).
// Per k32-step per wave: 8 A-frag + 3 B-frag loads (1KB contiguous each)
// + 24 MFMA. No LDS, no barriers. In-WG duplication served by L1,
// cross-WG by XCD L2. Compiler pipelines freely (unroll 2).
__global__ __launch_bounds__(512) void qkv_gemm_kernel(const u16* __restrict__ At, const u16* __restrict__ Wt,
                                                       u16* __restrict__ Qb, u16* __restrict__ Kb,
                                                       u16* __restrict__ Vt) {
  const int bid = blockIdx.x;       // 0..255
  const int xcd = bid & 7, seq = bid >> 3;
  const int mp = xcd * 8 + (seq >> 2);       // m-panel (256 rows), 0..63
  const int nt = seq & 3;                    // n-tile (192 cols)
  const int m0 = mp * 256, n0 = nt * 192;
  const int tid = threadIdx.x;
  const int wid = tid >> 6, lane = tid & 63;
  const int wm = wid >> 2, wn = wid & 3;     // 2M x 4N
  const int lrow = lane & 15, lkg = lane >> 4;

  const u16* Ab = At + (size_t)((mp * 16 + wm * 8) * 32) * 512 + (size_t)lane * 8;
  const u16* Bb = Wt + (size_t)((nt * 12 + wn * 3) * 32) * 512 + (size_t)lane * 8;

  f32x4 acc[8][3] = {};

#pragma unroll 2
  for (int k32 = 0; k32 < 32; ++k32) {
    bf16x8 a[8], b[3];
#pragma unroll
    for (int mf = 0; mf < 8; ++mf)
      a[mf] = *(const bf16x8*)(Ab + (size_t)(mf * 32 + k32) * 512);
#pragma unroll
    for (int nf = 0; nf < 3; ++nf)
      b[nf] = *(const bf16x8*)(Bb + (size_t)(nf * 32 + k32) * 512);
#pragma unroll
    for (int mf = 0; mf < 8; ++mf)
#pragma unroll
      for (int nf = 0; nf < 3; ++nf)
        acc[mf][nf] = __builtin_amdgcn_mfma_f32_16x16x32_bf16(a[mf], b[nf], acc[mf][nf], 0, 0, 0);
  }

  // ---- epilogue: cols 0..255 -> Q, 256..511 -> K, 512..767 -> V^T ----
#pragma unroll
  for (int mf = 0; mf < 8; ++mf)
#pragma unroll
    for (int nf = 0; nf < 3; ++nf) {
      const int gm = m0 + wm * 128 + mf * 16 + lkg * 4;
      const int c = n0 + wn * 48 + nf * 16 + lrow;
      if (c < 512) {
        u16* Dst = (c < 256) ? Qb : Kb;
        const int cc = c & 255;
#pragma unroll
        for (int r = 0; r < 4; ++r) Dst[(size_t)(gm + r) * 256 + cc] = f2bf(acc[mf][nf][r]);
      } else {
        const int h = c - 512;
        const int bb = gm >> 12, l = gm & 4095;
        u16x4 pk;
        pk.x = f2bf(acc[mf][nf][0]); pk.y = f2bf(acc[mf][nf][1]);
        pk.z = f2bf(acc[mf][nf][2]); pk.w = f2bf(acc[mf][nf][3]);
        *(u16x4*)&Vt[((size_t)bb * 256 + h) * 4096 + l] = pk;
      }
    }
}

// ---- kernel 2: WINDOWED decay attention ----------------------------------
// gamma^320 ~ 2.5e-15 => keys older than the aligned 256..319 window are
// numerically zero in fp32. QB=32 rows/WG, KB=64, 4 waves (256 thr).
__global__ __launch_bounds__(256) void attn_kernel(const u16* __restrict__ Qb, const u16* __restrict__ Kb,
                                                   const u16* __restrict__ Vt, float* __restrict__ out) {
  __shared__ u16 Plds[32 * 72];
  const int raw = blockIdx.x;                 // 0..511
  const int aid = (raw & 7) * 64 + (raw >> 3);  // XCD-chunked
  const int b = aid >> 7;                     // 0..3
  const int qt = aid & 127;                   // 0..127
  const int qb = qt * 32;
  const int tid = threadIdx.x;
  const int wid = tid >> 6, lane = tid & 63;
  const int lrow = lane & 15, lkg = lane >> 4, lk = lkg * 8;
  const size_t bQK = (size_t)b * 4096 * 256;

  bf16x8 qf[2][8];
#pragma unroll
  for (int mf = 0; mf < 2; ++mf) {
    const u16* Qrow = Qb + bQK + (size_t)(qb + mf * 16 + lrow) * 256;
#pragma unroll
    for (int kf = 0; kf < 8; ++kf) qf[mf][kf] = *(const bf16x8*)&Qrow[kf * 32 + lk];
  }

  int kstart = qb - 256; if (kstart < 0) kstart = 0; kstart &= ~63;
  const int njt = (qb + 32 - kstart + 63) >> 6;

  f32x4 oacc[2][4] = {};

  for (int jt = 0; jt < njt; ++jt) {
    const int kb = kstart + jt * 64;
    f32x4 s[2] = {};
    const u16* Krow = Kb + bQK + (size_t)(kb + wid * 16 + lrow) * 256;
#pragma unroll
    for (int kf = 0; kf < 8; ++kf) {
      const bf16x8 kfr = *(const bf16x8*)&Krow[kf * 32 + lk];
      s[0] = __builtin_amdgcn_mfma_f32_16x16x32_bf16(qf[0][kf], kfr, s[0], 0, 0, 0);
      s[1] = __builtin_amdgcn_mfma_f32_16x16x32_bf16(qf[1][kf], kfr, s[1], 0, 0, 0);
    }
    const int kg = kb + wid * 16 + lrow;
#pragma unroll
    for (int mf = 0; mf < 2; ++mf) {
      const int qg = qb + mf * 16 + lkg * 4;
#pragma unroll
      for (int r = 0; r < 4; ++r) {
        const int d = qg + r - kg;
        const float pv = (d >= 0) ? s[mf][r] * exp2f((float)d * L2GAMMA) * INV_SQRT_H : 0.0f;
        Plds[(mf * 16 + lkg * 4 + r) * 72 + wid * 16 + lrow] = f2bf(pv);
      }
    }
    __syncthreads();
#pragma unroll
    for (int ks = 0; ks < 2; ++ks) {
      bf16x8 pa[2];
      pa[0] = *(const bf16x8*)&Plds[(lrow) * 72 + ks * 32 + lk];
      pa[1] = *(const bf16x8*)&Plds[(16 + lrow) * 72 + ks * 32 + lk];
#pragma unroll
      for (int nf = 0; nf < 4; ++nf) {
        const bf16x8 vb = *(const bf16x8*)&Vt[((size_t)b * 256 + wid * 64 + nf * 16 + lrow) * 4096 + kb + ks * 32 + lk];
        oacc[0][nf] = __builtin_amdgcn_mfma_f32_16x16x32_bf16(pa[0], vb, oacc[0][nf], 0, 0, 0);
        oacc[1][nf] = __builtin_amdgcn_mfma_f32_16x16x32_bf16(pa[1], vb, oacc[1][nf], 0, 0, 0);
      }
    }
    __syncthreads();
  }

#pragma unroll
  for (int mf = 0; mf < 2; ++mf) {
    float* obase = out + ((size_t)b * 4096 + qb + mf * 16 + lkg * 4) * 256 + wid * 64 + lrow;
#pragma unroll
    for (int nf = 0; nf < 4; ++nf)
#pragma unroll
      for (int r = 0; r < 4; ++r)
        obase[(size_t)r * 256 + nf * 16] = oacc[mf][nf][r];
  }
}

extern "C" void kernel_launch(void* const* d_in, const int* in_sizes, int n_in,
                              void* d_out, int out_size, void* d_ws, size_t ws_size,
                              hipStream_t stream) {
  const float* x  = (const float*)d_in[0];
  const float* wq = (const float*)d_in[1];
  const float* wk = (const float*)d_in[2];
  const float* wv = (const float*)d_in[3];
  float* out = (float*)d_out;
  char* ws = (char*)d_ws;
  u16* At = (u16*)(ws);                          // 16384*1024*2 = 33,554,432 (frag-tiled)
  u16* Wt = (u16*)(ws + (size_t)33554432);       //   768*1024*2 =  1,572,864 (frag-tiled)
  u16* Qb = (u16*)(ws + (size_t)35127296);       // 16384*256*2  =  8,388,608
  u16* Kb = (u16*)(ws + (size_t)43515904);       //  8,388,608
  u16* Vt = (u16*)(ws + (size_t)51904512);       //  8,388,608  (end 60,293,120)

  hipLaunchKernelGGL(cvt_x_kernel, dim3(8192), dim3(256), 0, stream, x, At);
  hipLaunchKernelGGL(cvt_w_kernel, dim3(384), dim3(256), 0, stream, wq, wk, wv, Wt);
  hipLaunchKernelGGL(qkv_gemm_kernel, dim3(256), dim3(512), 0, stream, At, Wt, Qb, Kb, Vt);
  hipLaunchKernelGGL(attn_kernel, dim3(512), dim3(256), 0, stream, Qb, Kb, Vt, out);
}

// Round 16
// 79.176 us; speedup vs baseline: 1.1870x; 1.1870x over previous
//
#include <hip/hip_runtime.h>

typedef unsigned short u16;
typedef unsigned int u32;
typedef __attribute__((ext_vector_type(8))) short bf16x8;
typedef __attribute__((ext_vector_type(4))) float f32x4;
typedef __attribute__((ext_vector_type(4))) unsigned short u16x4;

#define DEVI __device__ __forceinline__
#define AS1 __attribute__((address_space(1)))
#define AS3 __attribute__((address_space(3)))

constexpr float L2GAMMA = -0.15200309344504997f; // log2(0.9)
constexpr float INV_SQRT_H = 0.0625f;            // 1/sqrt(256)

DEVI u16 f2bf(float x) {
  union { float f; unsigned u; } v; v.f = x;
  unsigned r = v.u + 0x7FFFu + ((v.u >> 16) & 1u);
  return (u16)(r >> 16);
}

// ---- kernel 0a: x fp32 -> bf16 (row-major) -------------------------------
__global__ void cvt_x_kernel(const float4* __restrict__ src, u16x4* __restrict__ dst, int n4) {
  int stride = gridDim.x * blockDim.x;
  for (int i = blockIdx.x * blockDim.x + threadIdx.x; i < n4; i += stride) {
    float4 v = src[i];
    u16x4 o; o.x = f2bf(v.x); o.y = f2bf(v.y); o.z = f2bf(v.z); o.w = f2bf(v.w);
    dst[i] = o;
  }
}

// ---- kernel 0b: W_Q|W_K|W_V (each 256x1024 fp32) -> Wb[768][1024] bf16 ---
__global__ void cvt_w_kernel(const float4* __restrict__ wq, const float4* __restrict__ wk,
                             const float4* __restrict__ wv, u16x4* __restrict__ dst) {
  int i = blockIdx.x * blockDim.x + threadIdx.x; // 0..196607
  int w = i >> 16, off = i & 65535;
  const float4* s = (w == 0) ? wq : ((w == 1) ? wk : wv);
  float4 v = s[off];
  u16x4 o; o.x = f2bf(v.x); o.y = f2bf(v.y); o.z = f2bf(v.z); o.w = f2bf(v.w);
  dst[(w << 16) + off] = o;
}

// ---- kernel 1: QKV GEMM  C[16384x768] = Xb * Wb^T ------------------------
// BM=128 BN=192 BK=64, 4 waves (256 thr, 1M x 4N; wave out 128x48).
// Grid 512 = 128 m-panels x 4 n-tiles = 2 WG/CU EXACT (LDS 80 KB).
// The round-15/14 lesson: 1-WG/CU phased designs expose barrier/drain
// latency with nothing to fill it. Here the schedule is simple (ONE
// __syncthreads per K-tile) and the co-resident second WG provides the
// overlap (m97/m114 mechanism).
// Double-buffered gload_lds staging: stages for t+1 (buf p^1) issue at the
// TOP of tile t (~900 cy cover); __syncthreads' vmcnt(0) drain at tile end
// is covered by the other WG.
// Race audit (1 barrier suffices): writes(t+1 -> p^1) never touch buf p
// being read; a wave's ds_reads of buf p are drained (compiler lgkmcnt)
// before its MFMAs, hence before its barrier; stages into buf p re-issue
// only after that barrier. gload_lds writes drain at the vmcnt(0) in
// __syncthreads before any wave passes -> generation switch is safe.
// Swizzle (R12/R14-verified, 0 conflicts): 128B rows = 8 x 16B slots,
// phys slot = j ^ (row&7); realized as pre-swizzled GLOBAL source +
// linear gload_lds dest (rule 21). Frag reads: bank = 4*phys (row*128B
// drops out), 8 slots x2 per 16-lane group = 2-way = free.
__global__ __launch_bounds__(256, 2) void qkv_gemm_kernel(const u16* __restrict__ Xb, const u16* __restrict__ Wb,
                                                          u16* __restrict__ Qb, u16* __restrict__ Kb,
                                                          u16* __restrict__ Vt) {
  __shared__ u16 Al[2][128 * 64];   // 2 x 16 KB
  __shared__ u16 Bl[2][192 * 64];   // 2 x 24 KB
  const int bid = blockIdx.x;       // 0..511
  const int rl = (bid & 7) * 64 + (bid >> 3);   // XCD-chunked bijection (512 = 8*64)
  const int mp = rl >> 2, nt = rl & 3;
  const int m0 = mp * 128, n0 = nt * 192;
  const int tid = threadIdx.x;
  const int wid = tid >> 6, lane = tid & 63;
  const int lrow = lane & 15, lkg = lane >> 4;
  const int srow32 = tid >> 3;      // staging: row within 32-row round
  const int sj = tid & 7;           // staging: linear 16B slot

  // rounds: A = 4 x 32 rows, B = 6 x 32 rows; per round each wave issues 1
  // gload_lds (1 KB). 10 issues/wave/K-tile, uniform.
#define STAGE_A(P, R, T) do { \
  const int row_ = (R) * 32 + srow32; \
  const u16* g_ = Xb + (size_t)(m0 + row_) * 1024 + (T) * 64 + ((sj ^ (row_ & 7)) << 3); \
  __builtin_amdgcn_global_load_lds((const AS1 void*)g_, (AS3 void*)&Al[P][((R) * 256 + tid) * 8], 16, 0, 0); \
} while (0)

#define STAGE_B(P, R, T) do { \
  const int row_ = (R) * 32 + srow32; \
  const u16* g_ = Wb + (size_t)(n0 + row_) * 1024 + (T) * 64 + ((sj ^ (row_ & 7)) << 3); \
  __builtin_amdgcn_global_load_lds((const AS1 void*)g_, (AS3 void*)&Bl[P][((R) * 256 + tid) * 8], 16, 0, 0); \
} while (0)

  f32x4 acc[8][3] = {};

  // ---- prologue: tile 0 -> buf 0 ----
  STAGE_A(0, 0, 0); STAGE_A(0, 1, 0); STAGE_A(0, 2, 0); STAGE_A(0, 3, 0);
  STAGE_B(0, 0, 0); STAGE_B(0, 1, 0); STAGE_B(0, 2, 0);
  STAGE_B(0, 3, 0); STAGE_B(0, 4, 0); STAGE_B(0, 5, 0);
  __syncthreads();

  for (int t = 0; t < 16; ++t) {
    const int p = t & 1;
    if (t < 15) {                                  // stage t+1 -> buf p^1
      STAGE_A(p ^ 1, 0, t + 1); STAGE_A(p ^ 1, 1, t + 1);
      STAGE_A(p ^ 1, 2, t + 1); STAGE_A(p ^ 1, 3, t + 1);
      STAGE_B(p ^ 1, 0, t + 1); STAGE_B(p ^ 1, 1, t + 1); STAGE_B(p ^ 1, 2, t + 1);
      STAGE_B(p ^ 1, 3, t + 1); STAGE_B(p ^ 1, 4, t + 1); STAGE_B(p ^ 1, 5, t + 1);
    }
    __builtin_amdgcn_sched_barrier(0);             // issues stay above compute
#pragma unroll
    for (int kk = 0; kk < 2; ++kk) {
      bf16x8 a[8], b[3];
#pragma unroll
      for (int mf = 0; mf < 8; ++mf) {
        const int r = mf * 16 + lrow;
        a[mf] = *(const bf16x8*)&Al[p][r * 64 + (((kk * 4 + lkg) ^ (r & 7)) << 3)];
      }
#pragma unroll
      for (int nf = 0; nf < 3; ++nf) {
        const int r = wid * 48 + nf * 16 + lrow;
        b[nf] = *(const bf16x8*)&Bl[p][r * 64 + (((kk * 4 + lkg) ^ (r & 7)) << 3)];
      }
      __builtin_amdgcn_s_setprio(1);
#pragma unroll
      for (int mf = 0; mf < 8; ++mf)
#pragma unroll
        for (int nf = 0; nf < 3; ++nf)
          acc[mf][nf] = __builtin_amdgcn_mfma_f32_16x16x32_bf16(a[mf], b[nf], acc[mf][nf], 0, 0, 0);
      __builtin_amdgcn_s_setprio(0);
    }
    __syncthreads();                               // vmcnt(0)+lgkmcnt(0)+barrier
  }

  // ---- epilogue: cols 0..255 -> Q, 256..511 -> K, 512..767 -> V^T ----
#pragma unroll
  for (int mf = 0; mf < 8; ++mf)
#pragma unroll
    for (int nf = 0; nf < 3; ++nf) {
      const int gm = m0 + mf * 16 + lkg * 4;
      const int c = n0 + wid * 48 + nf * 16 + lrow;
      if (c < 512) {
        u16* Dst = (c < 256) ? Qb : Kb;
        const int cc = c & 255;
#pragma unroll
        for (int r = 0; r < 4; ++r) Dst[(size_t)(gm + r) * 256 + cc] = f2bf(acc[mf][nf][r]);
      } else {
        const int h = c - 512;
        const int bb = gm >> 12, l = gm & 4095;
        u16x4 pk;
        pk.x = f2bf(acc[mf][nf][0]); pk.y = f2bf(acc[mf][nf][1]);
        pk.z = f2bf(acc[mf][nf][2]); pk.w = f2bf(acc[mf][nf][3]);
        *(u16x4*)&Vt[((size_t)bb * 256 + h) * 4096 + l] = pk;
      }
    }
}

// ---- kernel 2: WINDOWED decay attention ----------------------------------
// gamma^320 ~ 2.5e-15 => keys older than the aligned 256..319 window are
// numerically zero in fp32. QB=32 rows/WG, KB=64, 4 waves (256 thr).
__global__ __launch_bounds__(256) void attn_kernel(const u16* __restrict__ Qb, const u16* __restrict__ Kb,
                                                   const u16* __restrict__ Vt, float* __restrict__ out) {
  __shared__ u16 Plds[32 * 72];
  const int raw = blockIdx.x;                 // 0..511
  const int aid = (raw & 7) * 64 + (raw >> 3);  // XCD-chunked
  const int b = aid >> 7;                     // 0..3
  const int qt = aid & 127;                   // 0..127
  const int qb = qt * 32;
  const int tid = threadIdx.x;
  const int wid = tid >> 6, lane = tid & 63;
  const int lrow = lane & 15, lkg = lane >> 4, lk = lkg * 8;
  const size_t bQK = (size_t)b * 4096 * 256;

  bf16x8 qf[2][8];
#pragma unroll
  for (int mf = 0; mf < 2; ++mf) {
    const u16* Qrow = Qb + bQK + (size_t)(qb + mf * 16 + lrow) * 256;
#pragma unroll
    for (int kf = 0; kf < 8; ++kf) qf[mf][kf] = *(const bf16x8*)&Qrow[kf * 32 + lk];
  }

  int kstart = qb - 256; if (kstart < 0) kstart = 0; kstart &= ~63;
  const int njt = (qb + 32 - kstart + 63) >> 6;

  f32x4 oacc[2][4] = {};

  for (int jt = 0; jt < njt; ++jt) {
    const int kb = kstart + jt * 64;
    f32x4 s[2] = {};
    const u16* Krow = Kb + bQK + (size_t)(kb + wid * 16 + lrow) * 256;
#pragma unroll
    for (int kf = 0; kf < 8; ++kf) {
      const bf16x8 kfr = *(const bf16x8*)&Krow[kf * 32 + lk];
      s[0] = __builtin_amdgcn_mfma_f32_16x16x32_bf16(qf[0][kf], kfr, s[0], 0, 0, 0);
      s[1] = __builtin_amdgcn_mfma_f32_16x16x32_bf16(qf[1][kf], kfr, s[1], 0, 0, 0);
    }
    const int kg = kb + wid * 16 + lrow;
#pragma unroll
    for (int mf = 0; mf < 2; ++mf) {
      const int qg = qb + mf * 16 + lkg * 4;
#pragma unroll
      for (int r = 0; r < 4; ++r) {
        const int d = qg + r - kg;
        const float pv = (d >= 0) ? s[mf][r] * exp2f((float)d * L2GAMMA) * INV_SQRT_H : 0.0f;
        Plds[(mf * 16 + lkg * 4 + r) * 72 + wid * 16 + lrow] = f2bf(pv);
      }
    }
    __syncthreads();
#pragma unroll
    for (int ks = 0; ks < 2; ++ks) {
      bf16x8 pa[2];
      pa[0] = *(const bf16x8*)&Plds[(lrow) * 72 + ks * 32 + lk];
      pa[1] = *(const bf16x8*)&Plds[(16 + lrow) * 72 + ks * 32 + lk];
#pragma unroll
      for (int nf = 0; nf < 4; ++nf) {
        const bf16x8 vb = *(const bf16x8*)&Vt[((size_t)b * 256 + wid * 64 + nf * 16 + lrow) * 4096 + kb + ks * 32 + lk];
        oacc[0][nf] = __builtin_amdgcn_mfma_f32_16x16x32_bf16(pa[0], vb, oacc[0][nf], 0, 0, 0);
        oacc[1][nf] = __builtin_amdgcn_mfma_f32_16x16x32_bf16(pa[1], vb, oacc[1][nf], 0, 0, 0);
      }
    }
    __syncthreads();
  }

#pragma unroll
  for (int mf = 0; mf < 2; ++mf) {
    float* obase = out + ((size_t)b * 4096 + qb + mf * 16 + lkg * 4) * 256 + wid * 64 + lrow;
#pragma unroll
    for (int nf = 0; nf < 4; ++nf)
#pragma unroll
      for (int r = 0; r < 4; ++r)
        obase[(size_t)r * 256 + nf * 16] = oacc[mf][nf][r];
  }
}

extern "C" void kernel_launch(void* const* d_in, const int* in_sizes, int n_in,
                              void* d_out, int out_size, void* d_ws, size_t ws_size,
                              hipStream_t stream) {
  const float* x  = (const float*)d_in[0];
  const float* wq = (const float*)d_in[1];
  const float* wk = (const float*)d_in[2];
  const float* wv = (const float*)d_in[3];
  float* out = (float*)d_out;
  char* ws = (char*)d_ws;
  u16* Xb = (u16*)(ws);                          // 16384*1024*2 = 33,554,432
  u16* Wb = (u16*)(ws + (size_t)33554432);       //   768*1024*2 =  1,572,864
  u16* Qb = (u16*)(ws + (size_t)35127296);       // 16384*256*2  =  8,388,608
  u16* Kb = (u16*)(ws + (size_t)43515904);       //  8,388,608
  u16* Vt = (u16*)(ws + (size_t)51904512);       //  8,388,608  (end 60,293,120)

  hipLaunchKernelGGL(cvt_x_kernel, dim3(2048), dim3(256), 0, stream,
                     (const float4*)x, (u16x4*)Xb, 4194304);
  hipLaunchKernelGGL(cvt_w_kernel, dim3(768), dim3(256), 0, stream,
                     (const float4*)wq, (const float4*)wk, (const float4*)wv, (u16x4*)Wb);
  hipLaunchKernelGGL(qkv_gemm_kernel, dim3(512), dim3(256), 0, stream, Xb, Wb, Qb, Kb, Vt);
  hipLaunchKernelGGL(attn_kernel, dim3(512), dim3(256), 0, stream, Qb, Kb, Vt, out);
}